// Round 2
// baseline (425.959 us; speedup 1.0000x reference)
//
#include <hip/hip_runtime.h>

// ---- problem dims (hardcoded) ----
#define BATCH 8
#define SEQ   2048
#define DM    512
#define DK    64
#define NROW  (BATCH*SEQ)          // 16384 total rows
#define EPSV  1e-6f

typedef _Float16 f16x8 __attribute__((ext_vector_type(8)));
typedef _Float16 f16x4 __attribute__((ext_vector_type(4)));
typedef float    f32x4 __attribute__((ext_vector_type(4)));

#define MFMA16(a,b,c) __builtin_amdgcn_mfma_f32_16x16x32_f16(a, b, c, 0, 0, 0)

// ===================== K0: convert W to fp16 =====================
__global__ void wcvt(const float* __restrict__ wq, const float* __restrict__ wk,
                     const float* __restrict__ wv, _Float16* __restrict__ w16) {
    int idx = (blockIdx.x * 256 + threadIdx.x) * 4;   // grid 96 -> 98304 elems
    int z = idx >> 15;                                 // 32768 per matrix
    int off = idx & 32767;
    const float* src = (z == 0) ? wq : ((z == 1) ? wk : wv);
    float4 g = *reinterpret_cast<const float4*>(src + off);
    f16x4 h = { (_Float16)g.x, (_Float16)g.y, (_Float16)g.z, (_Float16)g.w };
    *reinterpret_cast<f16x4*>(w16 + idx) = h;
}

// ===================== K1: QKV projection (MFMA f16, barrier-free) =====================
__global__ __launch_bounds__(256) void proj(
    const float* __restrict__ query, const float* __restrict__ key,
    const float* __restrict__ value, const _Float16* __restrict__ w16,
    const float* __restrict__ bq, const float* __restrict__ bk, const float* __restrict__ bv,
    _Float16* __restrict__ q16, _Float16* __restrict__ k16, _Float16* __restrict__ vT16)
{
    __shared__ _Float16 xsh[64][72];   // only for the vT transpose epilogue

    const int t = threadIdx.x;
    const int wave = t >> 6, lane = t & 63;
    const int n16 = lane & 15, quad = lane >> 4;
    const int z = blockIdx.y;
    const float* in   = (z == 0) ? query : ((z == 1) ? key : value);
    const float* bias = (z == 0) ? bq    : ((z == 1) ? bk  : bv);
    const _Float16* wz = w16 + z * (DK * DM);
    const int row0 = blockIdx.x * 64;
    const float* abase = in + (size_t)(row0 + wave * 16 + n16) * DM + quad * 8;

    f32x4 acc[4] = {};   // 4 n-tiles of 16 cols each

    float4 p0 = *reinterpret_cast<const float4*>(abase);
    float4 p1 = *reinterpret_cast<const float4*>(abase + 4);
    float4 p2 = *reinterpret_cast<const float4*>(abase + 32);
    float4 p3 = *reinterpret_cast<const float4*>(abase + 36);

    #pragma unroll 2
    for (int kk = 0; kk < DM; kk += 64) {
        f16x8 a0 = { (_Float16)p0.x, (_Float16)p0.y, (_Float16)p0.z, (_Float16)p0.w,
                     (_Float16)p1.x, (_Float16)p1.y, (_Float16)p1.z, (_Float16)p1.w };
        f16x8 a1 = { (_Float16)p2.x, (_Float16)p2.y, (_Float16)p2.z, (_Float16)p2.w,
                     (_Float16)p3.x, (_Float16)p3.y, (_Float16)p3.z, (_Float16)p3.w };
        if (kk < DM - 64) {
            p0 = *reinterpret_cast<const float4*>(abase + kk + 64);
            p1 = *reinterpret_cast<const float4*>(abase + kk + 68);
            p2 = *reinterpret_cast<const float4*>(abase + kk + 96);
            p3 = *reinterpret_cast<const float4*>(abase + kk + 100);
        }
        #pragma unroll
        for (int nt = 0; nt < 4; ++nt) {
            const _Float16* bbase = wz + (size_t)(nt * 16 + n16) * DM + kk + quad * 8;
            f16x8 b0 = *reinterpret_cast<const f16x8*>(bbase);
            f16x8 b1 = *reinterpret_cast<const f16x8*>(bbase + 32);
            acc[nt] = MFMA16(a0, b0, acc[nt]);
            acc[nt] = MFMA16(a1, b1, acc[nt]);
        }
    }

    const int batch = row0 >> 11, row0s = row0 & (SEQ - 1);
    if (z < 2) {
        _Float16* out = (z == 0) ? q16 : k16;
        #pragma unroll
        for (int nt = 0; nt < 4; ++nt) {
            float bzv = bias[nt * 16 + n16];
            #pragma unroll
            for (int r = 0; r < 4; ++r) {
                int grow = row0 + wave * 16 + quad * 4 + r;   // C layout: row=quad*4+reg
                out[(size_t)grow * DK + nt * 16 + n16] = (_Float16)(acc[nt][r] + bzv);
            }
        }
    } else {
        #pragma unroll
        for (int nt = 0; nt < 4; ++nt) {
            float bzv = bias[nt * 16 + n16];
            #pragma unroll
            for (int r = 0; r < 4; ++r)
                xsh[nt * 16 + n16][wave * 16 + quad * 4 + r] = (_Float16)(acc[nt][r] + bzv);
        }
        __syncthreads();
        int d = t >> 2, s0 = (t & 3) * 16;
        _Float16* dst = vT16 + ((size_t)(batch * DK + d)) * SEQ + row0s + s0;
        f16x8 h0, h1;
        #pragma unroll
        for (int j = 0; j < 8; ++j) { h0[j] = xsh[d][s0 + j]; h1[j] = xsh[d][s0 + 8 + j]; }
        *reinterpret_cast<f16x8*>(dst)     = h0;
        *reinterpret_cast<f16x8*>(dst + 8) = h1;
    }
}

// ===================== K2: fused attention =====================
// Occupancy round: RT 16 -> 8 (LDS 70.7 KB -> 35.1 KB => 4 blocks/CU, 32 waves/CU).
// Phase-1/3 MFMA A-rows 8..15 are duplicates (n16&7), outputs masked at store.
#define RT  8
#define SCH 2056   // fp16 row pitch: 4112 B (16B-aligned)

__global__ __launch_bounds__(512, 8) void attn(
    const _Float16* __restrict__ q16,   // [16384][64]
    const _Float16* __restrict__ k16,   // [16384][64]
    const _Float16* __restrict__ vT16,  // [8][64][2048]
    const int* __restrict__ mask,       // [8][2048][2048]
    float* __restrict__ attno,          // [16384][64]
    float* __restrict__ aw)             // [8][2048][2048]
{
    __shared__ _Float16 sc[RT][SCH];    // scores -> masked s -> exp(s-m), fp16 (~33 KB)
    __shared__ float red[4][RT][17];    // phase-3 partial-O reduction (padded)
    __shared__ float st_il[RT];

    const int t = threadIdx.x;
    const int wave = t >> 6, lane = t & 63;
    const int n16 = lane & 15, quad = lane >> 4;
    const int row0 = blockIdx.x * RT;
    const int batch = row0 >> 11, row0s = row0 & (SEQ - 1);

    // ---------- phase 0: mask -> register bitmask (hides L3/HBM latency under QK) ----------
    // wave w owns row w; this lane covers keys {it*256 + lane*4 .. +3}, it=0..7
    unsigned int mb = 0;
    {
        const int4* mr = reinterpret_cast<const int4*>(
            mask + (size_t)batch * SEQ * SEQ + (size_t)(row0s + wave) * SEQ);
        #pragma unroll
        for (int it = 0; it < 8; ++it) {
            int4 a = mr[it * 64 + lane];
            mb |= ((a.x != 0) ? 1u : 0u) << (it * 4 + 0);
            mb |= ((a.y != 0) ? 1u : 0u) << (it * 4 + 1);
            mb |= ((a.z != 0) ? 1u : 0u) << (it * 4 + 2);
            mb |= ((a.w != 0) ? 1u : 0u) << (it * 4 + 3);
        }
    }

    // ---------- phase 1: scaled scores -> sc (fp16); 128 keys/iter, depth-2 pipe ----------
    {
        // A rows 8..15 duplicate rows 0..7 (block only owns 8 query rows)
        const _Float16* qb = q16 + (size_t)(row0 + (n16 & 7)) * DK + quad * 8;
        f16x8 aq0 = *reinterpret_cast<const f16x8*>(qb);
        f16x8 aq1 = *reinterpret_cast<const f16x8*>(qb + 32);
        const _Float16* kbase = k16 + (size_t)(batch * SEQ) * DK
                              + (size_t)(wave * 16 + n16) * DK + quad * 8;
        f16x8 b0[2], b1[2];
        b0[0] = *reinterpret_cast<const f16x8*>(kbase);
        b1[0] = *reinterpret_cast<const f16x8*>(kbase + 32);
        b0[1] = *reinterpret_cast<const f16x8*>(kbase + 128 * DK);
        b1[1] = *reinterpret_cast<const f16x8*>(kbase + 128 * DK + 32);
        #pragma unroll
        for (int c = 0; c < 16; ++c) {
            int cur = c & 1;
            f16x8 cb0 = b0[cur], cb1 = b1[cur];
            if (c < 14) {   // depth-2: keep two chunk-loads in flight
                b0[cur] = *reinterpret_cast<const f16x8*>(kbase + (size_t)(c + 2) * 128 * DK);
                b1[cur] = *reinterpret_cast<const f16x8*>(kbase + (size_t)(c + 2) * 128 * DK + 32);
            }
            f32x4 acc = {};
            acc = MFMA16(aq0, cb0, acc);
            acc = MFMA16(aq1, cb1, acc);
            int col = c * 128 + wave * 16 + n16;
            if (quad < 2) {   // rows 0..7 are real; 8..15 are duplicates
                #pragma unroll
                for (int r = 0; r < 4; ++r)
                    sc[quad * 4 + r][col] = (_Float16)(acc[r] * 0.125f);
            }
        }
    }
    __syncthreads();

    // ---------- phase 2: pure LDS/VALU softmax (mask already in registers) ----------
    {
        const int row = wave;

        // pass A: mask/eps fill -> writeback fp16; track max
        float vmax = -3.4e38f;
        #pragma unroll
        for (int it = 0; it < 8; ++it) {
            int j = it * 64 + lane;
            f16x4 s4 = *reinterpret_cast<const f16x4*>(&sc[row][j * 4]);
            float s0 = (float)s4[0], s1 = (float)s4[1], s2 = (float)s4[2], s3 = (float)s4[3];
            s0 = (!((mb >> (it * 4 + 0)) & 1u) || s0 == 0.0f) ? EPSV : s0;
            s1 = (!((mb >> (it * 4 + 1)) & 1u) || s1 == 0.0f) ? EPSV : s1;
            s2 = (!((mb >> (it * 4 + 2)) & 1u) || s2 == 0.0f) ? EPSV : s2;
            s3 = (!((mb >> (it * 4 + 3)) & 1u) || s3 == 0.0f) ? EPSV : s3;
            f16x4 h = { (_Float16)s0, (_Float16)s1, (_Float16)s2, (_Float16)s3 };
            *reinterpret_cast<f16x4*>(&sc[row][j * 4]) = h;
            vmax = fmaxf(vmax, fmaxf(fmaxf(s0, s1), fmaxf(s2, s3)));
        }
        #pragma unroll
        for (int off = 32; off; off >>= 1) vmax = fmaxf(vmax, __shfl_xor(vmax, off));

        // pass B: exp(s - m) -> writeback fp16; track sum
        float vsum = 0.0f;
        #pragma unroll
        for (int it = 0; it < 8; ++it) {
            int j = it * 64 + lane;
            f16x4 s4 = *reinterpret_cast<const f16x4*>(&sc[row][j * 4]);
            float e0 = __expf((float)s4[0] - vmax), e1 = __expf((float)s4[1] - vmax);
            float e2 = __expf((float)s4[2] - vmax), e3 = __expf((float)s4[3] - vmax);
            f16x4 h = { (_Float16)e0, (_Float16)e1, (_Float16)e2, (_Float16)e3 };
            *reinterpret_cast<f16x4*>(&sc[row][j * 4]) = h;
            vsum += (e0 + e1) + (e2 + e3);
        }
        #pragma unroll
        for (int off = 32; off; off >>= 1) vsum += __shfl_xor(vsum, off);
        float il = 1.0f / vsum;
        if (lane == 0) st_il[row] = il;

        // pass C: p = e * il -> aw (nontemporal float4 — write-once data)
        float* awrow = aw + (size_t)batch * SEQ * SEQ + (size_t)(row0s + row) * SEQ;
        #pragma unroll
        for (int it = 0; it < 8; ++it) {
            int j = it * 64 + lane;
            f16x4 e4 = *reinterpret_cast<const f16x4*>(&sc[row][j * 4]);
            f32x4 p4 = { (float)e4[0] * il, (float)e4[1] * il,
                         (float)e4[2] * il, (float)e4[3] * il };
            __builtin_nontemporal_store(p4, reinterpret_cast<f32x4*>(awrow + j * 4));
        }
    }
    __syncthreads();

    // ---------- phase 3: O = (E V) * il — key-split, depth-2 pipe ----------
    {
        const int dblk = wave & 3, khalf = wave >> 2;
        f32x4 oacc = {};
        const _Float16* vbase = vT16 + ((size_t)(batch * DK + dblk * 16 + n16)) * SEQ
                              + khalf * 1024 + quad * 8;
        const _Float16* scrow = &sc[n16 & 7][khalf * 1024];   // A rows 8..15 duplicate 0..7
        f16x8 bv0[2], bv1[2];
        bv0[0] = *reinterpret_cast<const f16x8*>(vbase);
        bv1[0] = *reinterpret_cast<const f16x8*>(vbase + 32);
        bv0[1] = *reinterpret_cast<const f16x8*>(vbase + 64);
        bv1[1] = *reinterpret_cast<const f16x8*>(vbase + 96);
        #pragma unroll
        for (int c = 0; c < 16; ++c) {
            int cur = c & 1;
            f16x8 cb0 = bv0[cur], cb1 = bv1[cur];
            if (c < 14) {
                bv0[cur] = *reinterpret_cast<const f16x8*>(vbase + (c + 2) * 64);
                bv1[cur] = *reinterpret_cast<const f16x8*>(vbase + (c + 2) * 64 + 32);
            }
            f16x8 a0 = *reinterpret_cast<const f16x8*>(scrow + c * 64 + quad * 8);
            f16x8 a1 = *reinterpret_cast<const f16x8*>(scrow + c * 64 + 32 + quad * 8);
            oacc = MFMA16(a0, cb0, oacc);
            oacc = MFMA16(a1, cb1, oacc);
        }
        if (khalf == 1 && quad < 2) {      // rows 0..7 real
            #pragma unroll
            for (int r = 0; r < 4; ++r)
                red[dblk][quad * 4 + r][n16] = oacc[r];
        }
        __syncthreads();
        if (khalf == 0 && quad < 2) {
            #pragma unroll
            for (int r = 0; r < 4; ++r) {
                int row = quad * 4 + r;
                float o = oacc[r] + red[dblk][row][n16];
                attno[(size_t)(row0 + row) * DK + dblk * 16 + n16] = o * st_il[row];
            }
        }
    }
}

// ===================== launch =====================
extern "C" void kernel_launch(void* const* d_in, const int* in_sizes, int n_in,
                              void* d_out, int out_size, void* d_ws, size_t ws_size,
                              hipStream_t stream) {
    const float* query = (const float*)d_in[0];
    const float* key   = (const float*)d_in[1];
    const float* value = (const float*)d_in[2];
    const int*   amask = (const int*)d_in[3];
    const float* Wq = (const float*)d_in[4];
    const float* bq = (const float*)d_in[5];
    const float* Wk = (const float*)d_in[6];
    const float* bk = (const float*)d_in[7];
    const float* Wv = (const float*)d_in[8];
    const float* bv = (const float*)d_in[9];

    float* attno = (float*)d_out;                      // [16384][64]
    float* aw    = attno + (size_t)NROW * DK;          // [8][2048][2048]

    char* ws = (char*)d_ws;
    _Float16* q16  = (_Float16*)(ws);                  // 2 MB
    _Float16* k16  = (_Float16*)(ws + (size_t)2097152);// 2 MB
    _Float16* vT16 = (_Float16*)(ws + (size_t)4194304);// 2 MB
    _Float16* w16  = (_Float16*)(ws + (size_t)6291456);// 192 KB

    wcvt<<<96, 256, 0, stream>>>(Wq, Wk, Wv, w16);
    proj<<<dim3(NROW / 64, 3), 256, 0, stream>>>(query, key, value, w16,
                                                 bq, bk, bv, q16, k16, vT16);
    attn<<<NROW / RT, 512, 0, stream>>>(q16, k16, vT16, amask, attno, aw);
}

// Round 3
// 412.089 us; speedup vs baseline: 1.0337x; 1.0337x over previous
//
#include <hip/hip_runtime.h>

// ---- problem dims (hardcoded) ----
#define BATCH 8
#define SEQ   2048
#define DM    512
#define DK    64
#define NROW  (BATCH*SEQ)          // 16384 total rows
#define EPSV  1e-6f

typedef _Float16 f16x8 __attribute__((ext_vector_type(8)));
typedef _Float16 f16x4 __attribute__((ext_vector_type(4)));
typedef float    f32x4 __attribute__((ext_vector_type(4)));

#define MFMA16(a,b,c) __builtin_amdgcn_mfma_f32_16x16x32_f16(a, b, c, 0, 0, 0)

// ===================== K0: convert W to fp16 =====================
__global__ void wcvt(const float* __restrict__ wq, const float* __restrict__ wk,
                     const float* __restrict__ wv, _Float16* __restrict__ w16) {
    int idx = (blockIdx.x * 256 + threadIdx.x) * 4;   // grid 96 -> 98304 elems
    int z = idx >> 15;                                 // 32768 per matrix
    int off = idx & 32767;
    const float* src = (z == 0) ? wq : ((z == 1) ? wk : wv);
    float4 g = *reinterpret_cast<const float4*>(src + off);
    f16x4 h = { (_Float16)g.x, (_Float16)g.y, (_Float16)g.z, (_Float16)g.w };
    *reinterpret_cast<f16x4*>(w16 + idx) = h;
}

// ===================== K1: QKV projection (MFMA f16) =====================
// Occupancy round: 32 rows/block (grid 512x3 = 1536 blocks -> 6 blocks/CU, 24 waves/CU).
// Wave pairs: waves {0,1} rows 0-15, waves {2,3} rows 16-31; (w&1) picks col half (2 n-tiles).
__global__ __launch_bounds__(256) void proj(
    const float* __restrict__ query, const float* __restrict__ key,
    const float* __restrict__ value, const _Float16* __restrict__ w16,
    const float* __restrict__ bq, const float* __restrict__ bk, const float* __restrict__ bv,
    _Float16* __restrict__ q16, _Float16* __restrict__ k16, _Float16* __restrict__ vT16)
{
    __shared__ _Float16 xsh[64][36];   // only for the vT transpose epilogue (cols x 32 rows + pad)

    const int t = threadIdx.x;
    const int wave = t >> 6, lane = t & 63;
    const int n16 = lane & 15, quad = lane >> 4;
    const int z = blockIdx.y;
    const float* in   = (z == 0) ? query : ((z == 1) ? key : value);
    const float* bias = (z == 0) ? bq    : ((z == 1) ? bk  : bv);
    const _Float16* wz = w16 + z * (DK * DM);
    const int row0 = blockIdx.x * 32;
    const int row_base = row0 + (wave >> 1) * 16;
    const int nt0 = (wave & 1) * 2;                   // this wave's two n-tiles: nt0, nt0+1
    const float* abase = in + (size_t)(row_base + n16) * DM + quad * 8;

    f32x4 acc[2] = {};   // 2 n-tiles of 16 cols each

    float4 p0 = *reinterpret_cast<const float4*>(abase);
    float4 p1 = *reinterpret_cast<const float4*>(abase + 4);
    float4 p2 = *reinterpret_cast<const float4*>(abase + 32);
    float4 p3 = *reinterpret_cast<const float4*>(abase + 36);

    #pragma unroll 2
    for (int kk = 0; kk < DM; kk += 64) {
        f16x8 a0 = { (_Float16)p0.x, (_Float16)p0.y, (_Float16)p0.z, (_Float16)p0.w,
                     (_Float16)p1.x, (_Float16)p1.y, (_Float16)p1.z, (_Float16)p1.w };
        f16x8 a1 = { (_Float16)p2.x, (_Float16)p2.y, (_Float16)p2.z, (_Float16)p2.w,
                     (_Float16)p3.x, (_Float16)p3.y, (_Float16)p3.z, (_Float16)p3.w };
        if (kk < DM - 64) {
            p0 = *reinterpret_cast<const float4*>(abase + kk + 64);
            p1 = *reinterpret_cast<const float4*>(abase + kk + 68);
            p2 = *reinterpret_cast<const float4*>(abase + kk + 96);
            p3 = *reinterpret_cast<const float4*>(abase + kk + 100);
        }
        #pragma unroll
        for (int i = 0; i < 2; ++i) {
            const _Float16* bbase = wz + (size_t)((nt0 + i) * 16 + n16) * DM + kk + quad * 8;
            f16x8 b0 = *reinterpret_cast<const f16x8*>(bbase);
            f16x8 b1 = *reinterpret_cast<const f16x8*>(bbase + 32);
            acc[i] = MFMA16(a0, b0, acc[i]);
            acc[i] = MFMA16(a1, b1, acc[i]);
        }
    }

    const int batch = row0 >> 11, row0s = row0 & (SEQ - 1);
    if (z < 2) {
        _Float16* out = (z == 0) ? q16 : k16;
        #pragma unroll
        for (int i = 0; i < 2; ++i) {
            float bzv = bias[(nt0 + i) * 16 + n16];
            #pragma unroll
            for (int r = 0; r < 4; ++r) {
                int grow = row_base + quad * 4 + r;   // C layout: row=quad*4+reg
                out[(size_t)grow * DK + (nt0 + i) * 16 + n16] = (_Float16)(acc[i][r] + bzv);
            }
        }
    } else {
        #pragma unroll
        for (int i = 0; i < 2; ++i) {
            float bzv = bias[(nt0 + i) * 16 + n16];
            #pragma unroll
            for (int r = 0; r < 4; ++r)
                xsh[(nt0 + i) * 16 + n16][(wave >> 1) * 16 + quad * 4 + r]
                    = (_Float16)(acc[i][r] + bzv);
        }
        __syncthreads();
        int d = t >> 2, s0 = (t & 3) * 8;             // 64 cols x 4 chunks of 8
        _Float16* dst = vT16 + ((size_t)(batch * DK + d)) * SEQ + row0s + s0;
        f16x8 h0;
        #pragma unroll
        for (int j = 0; j < 8; ++j) h0[j] = xsh[d][s0 + j];
        *reinterpret_cast<f16x8*>(dst) = h0;
    }
}

// ===================== K2: fused attention =====================
// RT=8 (LDS 35.1 KB => 4 blocks/CU by LDS). launch_bounds min-waves kept at 4:
// (512,8) forced VGPR->32 and spilled (+76 MB HBM scratch traffic, round-2 post-mortem).
// Natural allocation ~56 VGPR <= 64 still permits 32 waves/CU at runtime.
#define RT  8
#define SCH 2056   // fp16 row pitch: 4112 B (16B-aligned)

__global__ __launch_bounds__(512, 4) void attn(
    const _Float16* __restrict__ q16,   // [16384][64]
    const _Float16* __restrict__ k16,   // [16384][64]
    const _Float16* __restrict__ vT16,  // [8][64][2048]
    const int* __restrict__ mask,       // [8][2048][2048]
    float* __restrict__ attno,          // [16384][64]
    float* __restrict__ aw)             // [8][2048][2048]
{
    __shared__ _Float16 sc[RT][SCH];    // scores -> masked s -> exp(s-m), fp16 (~33 KB)
    __shared__ float red[4][RT][17];    // phase-3 partial-O reduction (padded)
    __shared__ float st_il[RT];

    const int t = threadIdx.x;
    const int wave = t >> 6, lane = t & 63;
    const int n16 = lane & 15, quad = lane >> 4;
    const int row0 = blockIdx.x * RT;
    const int batch = row0 >> 11, row0s = row0 & (SEQ - 1);

    // ---------- phase 0: mask -> register bitmask (hides L3/HBM latency under QK) ----------
    // wave w owns row w; this lane covers keys {it*256 + lane*4 .. +3}, it=0..7
    unsigned int mb = 0;
    {
        const int4* mr = reinterpret_cast<const int4*>(
            mask + (size_t)batch * SEQ * SEQ + (size_t)(row0s + wave) * SEQ);
        #pragma unroll
        for (int it = 0; it < 8; ++it) {
            int4 a = mr[it * 64 + lane];
            mb |= ((a.x != 0) ? 1u : 0u) << (it * 4 + 0);
            mb |= ((a.y != 0) ? 1u : 0u) << (it * 4 + 1);
            mb |= ((a.z != 0) ? 1u : 0u) << (it * 4 + 2);
            mb |= ((a.w != 0) ? 1u : 0u) << (it * 4 + 3);
        }
    }

    // ---------- phase 1: scaled scores -> sc (fp16); 128 keys/iter, depth-2 pipe ----------
    {
        // A rows 8..15 duplicate rows 0..7 (block only owns 8 query rows)
        const _Float16* qb = q16 + (size_t)(row0 + (n16 & 7)) * DK + quad * 8;
        f16x8 aq0 = *reinterpret_cast<const f16x8*>(qb);
        f16x8 aq1 = *reinterpret_cast<const f16x8*>(qb + 32);
        const _Float16* kbase = k16 + (size_t)(batch * SEQ) * DK
                              + (size_t)(wave * 16 + n16) * DK + quad * 8;
        f16x8 b0[2], b1[2];
        b0[0] = *reinterpret_cast<const f16x8*>(kbase);
        b1[0] = *reinterpret_cast<const f16x8*>(kbase + 32);
        b0[1] = *reinterpret_cast<const f16x8*>(kbase + 128 * DK);
        b1[1] = *reinterpret_cast<const f16x8*>(kbase + 128 * DK + 32);
        #pragma unroll
        for (int c = 0; c < 16; ++c) {
            int cur = c & 1;
            f16x8 cb0 = b0[cur], cb1 = b1[cur];
            if (c < 14) {   // depth-2: keep two chunk-loads in flight
                b0[cur] = *reinterpret_cast<const f16x8*>(kbase + (size_t)(c + 2) * 128 * DK);
                b1[cur] = *reinterpret_cast<const f16x8*>(kbase + (size_t)(c + 2) * 128 * DK + 32);
            }
            f32x4 acc = {};
            acc = MFMA16(aq0, cb0, acc);
            acc = MFMA16(aq1, cb1, acc);
            int col = c * 128 + wave * 16 + n16;
            if (quad < 2) {   // rows 0..7 are real; 8..15 are duplicates
                #pragma unroll
                for (int r = 0; r < 4; ++r)
                    sc[quad * 4 + r][col] = (_Float16)(acc[r] * 0.125f);
            }
        }
    }
    __syncthreads();

    // ---------- phase 2: pure LDS/VALU softmax (mask already in registers) ----------
    {
        const int row = wave;

        // pass A: mask/eps fill -> writeback fp16; track max
        float vmax = -3.4e38f;
        #pragma unroll
        for (int it = 0; it < 8; ++it) {
            int j = it * 64 + lane;
            f16x4 s4 = *reinterpret_cast<const f16x4*>(&sc[row][j * 4]);
            float s0 = (float)s4[0], s1 = (float)s4[1], s2 = (float)s4[2], s3 = (float)s4[3];
            s0 = (!((mb >> (it * 4 + 0)) & 1u) || s0 == 0.0f) ? EPSV : s0;
            s1 = (!((mb >> (it * 4 + 1)) & 1u) || s1 == 0.0f) ? EPSV : s1;
            s2 = (!((mb >> (it * 4 + 2)) & 1u) || s2 == 0.0f) ? EPSV : s2;
            s3 = (!((mb >> (it * 4 + 3)) & 1u) || s3 == 0.0f) ? EPSV : s3;
            f16x4 h = { (_Float16)s0, (_Float16)s1, (_Float16)s2, (_Float16)s3 };
            *reinterpret_cast<f16x4*>(&sc[row][j * 4]) = h;
            vmax = fmaxf(vmax, fmaxf(fmaxf(s0, s1), fmaxf(s2, s3)));
        }
        #pragma unroll
        for (int off = 32; off; off >>= 1) vmax = fmaxf(vmax, __shfl_xor(vmax, off));

        // pass B: exp(s - m) -> writeback fp16; track sum
        float vsum = 0.0f;
        #pragma unroll
        for (int it = 0; it < 8; ++it) {
            int j = it * 64 + lane;
            f16x4 s4 = *reinterpret_cast<const f16x4*>(&sc[row][j * 4]);
            float e0 = __expf((float)s4[0] - vmax), e1 = __expf((float)s4[1] - vmax);
            float e2 = __expf((float)s4[2] - vmax), e3 = __expf((float)s4[3] - vmax);
            f16x4 h = { (_Float16)e0, (_Float16)e1, (_Float16)e2, (_Float16)e3 };
            *reinterpret_cast<f16x4*>(&sc[row][j * 4]) = h;
            vsum += (e0 + e1) + (e2 + e3);
        }
        #pragma unroll
        for (int off = 32; off; off >>= 1) vsum += __shfl_xor(vsum, off);
        float il = 1.0f / vsum;
        if (lane == 0) st_il[row] = il;

        // pass C: p = e * il -> aw (nontemporal float4 — write-once data)
        float* awrow = aw + (size_t)batch * SEQ * SEQ + (size_t)(row0s + row) * SEQ;
        #pragma unroll
        for (int it = 0; it < 8; ++it) {
            int j = it * 64 + lane;
            f16x4 e4 = *reinterpret_cast<const f16x4*>(&sc[row][j * 4]);
            f32x4 p4 = { (float)e4[0] * il, (float)e4[1] * il,
                         (float)e4[2] * il, (float)e4[3] * il };
            __builtin_nontemporal_store(p4, reinterpret_cast<f32x4*>(awrow + j * 4));
        }
    }
    __syncthreads();

    // ---------- phase 3: O = (E V) * il — key-split, depth-2 pipe ----------
    {
        const int dblk = wave & 3, khalf = wave >> 2;
        f32x4 oacc = {};
        const _Float16* vbase = vT16 + ((size_t)(batch * DK + dblk * 16 + n16)) * SEQ
                              + khalf * 1024 + quad * 8;
        const _Float16* scrow = &sc[n16 & 7][khalf * 1024];   // A rows 8..15 duplicate 0..7
        f16x8 bv0[2], bv1[2];
        bv0[0] = *reinterpret_cast<const f16x8*>(vbase);
        bv1[0] = *reinterpret_cast<const f16x8*>(vbase + 32);
        bv0[1] = *reinterpret_cast<const f16x8*>(vbase + 64);
        bv1[1] = *reinterpret_cast<const f16x8*>(vbase + 96);
        #pragma unroll
        for (int c = 0; c < 16; ++c) {
            int cur = c & 1;
            f16x8 cb0 = bv0[cur], cb1 = bv1[cur];
            if (c < 14) {
                bv0[cur] = *reinterpret_cast<const f16x8*>(vbase + (c + 2) * 64);
                bv1[cur] = *reinterpret_cast<const f16x8*>(vbase + (c + 2) * 64 + 32);
            }
            f16x8 a0 = *reinterpret_cast<const f16x8*>(scrow + c * 64 + quad * 8);
            f16x8 a1 = *reinterpret_cast<const f16x8*>(scrow + c * 64 + 32 + quad * 8);
            oacc = MFMA16(a0, cb0, oacc);
            oacc = MFMA16(a1, cb1, oacc);
        }
        if (khalf == 1 && quad < 2) {      // rows 0..7 real
            #pragma unroll
            for (int r = 0; r < 4; ++r)
                red[dblk][quad * 4 + r][n16] = oacc[r];
        }
        __syncthreads();
        if (khalf == 0 && quad < 2) {
            #pragma unroll
            for (int r = 0; r < 4; ++r) {
                int row = quad * 4 + r;
                float o = oacc[r] + red[dblk][row][n16];
                attno[(size_t)(row0 + row) * DK + dblk * 16 + n16] = o * st_il[row];
            }
        }
    }
}

// ===================== launch =====================
extern "C" void kernel_launch(void* const* d_in, const int* in_sizes, int n_in,
                              void* d_out, int out_size, void* d_ws, size_t ws_size,
                              hipStream_t stream) {
    const float* query = (const float*)d_in[0];
    const float* key   = (const float*)d_in[1];
    const float* value = (const float*)d_in[2];
    const int*   amask = (const int*)d_in[3];
    const float* Wq = (const float*)d_in[4];
    const float* bq = (const float*)d_in[5];
    const float* Wk = (const float*)d_in[6];
    const float* bk = (const float*)d_in[7];
    const float* Wv = (const float*)d_in[8];
    const float* bv = (const float*)d_in[9];

    float* attno = (float*)d_out;                      // [16384][64]
    float* aw    = attno + (size_t)NROW * DK;          // [8][2048][2048]

    char* ws = (char*)d_ws;
    _Float16* q16  = (_Float16*)(ws);                  // 2 MB
    _Float16* k16  = (_Float16*)(ws + (size_t)2097152);// 2 MB
    _Float16* vT16 = (_Float16*)(ws + (size_t)4194304);// 2 MB
    _Float16* w16  = (_Float16*)(ws + (size_t)6291456);// 192 KB

    wcvt<<<96, 256, 0, stream>>>(Wq, Wk, Wv, w16);
    proj<<<dim3(NROW / 32, 3), 256, 0, stream>>>(query, key, value, w16,
                                                 bq, bk, bv, q16, k16, vT16);
    attn<<<NROW / RT, 512, 0, stream>>>(q16, k16, vT16, amask, attno, aw);
}

// Round 4
// 377.552 us; speedup vs baseline: 1.1282x; 1.0915x over previous
//
#include <hip/hip_runtime.h>

// ---- problem dims (hardcoded) ----
#define BATCH 8
#define SEQ   2048
#define DM    512
#define DK    64
#define NROW  (BATCH*SEQ)          // 16384 total rows
#define EPSV  1e-6f

typedef _Float16 f16x8 __attribute__((ext_vector_type(8)));
typedef _Float16 f16x4 __attribute__((ext_vector_type(4)));
typedef float    f32x4 __attribute__((ext_vector_type(4)));

#define MFMA16(a,b,c) __builtin_amdgcn_mfma_f32_16x16x32_f16(a, b, c, 0, 0, 0)

// ===================== K0: convert W to fp16 =====================
__global__ void wcvt(const float* __restrict__ wq, const float* __restrict__ wk,
                     const float* __restrict__ wv, _Float16* __restrict__ w16) {
    int idx = (blockIdx.x * 256 + threadIdx.x) * 4;   // grid 96 -> 98304 elems
    int z = idx >> 15;                                 // 32768 per matrix
    int off = idx & 32767;
    const float* src = (z == 0) ? wq : ((z == 1) ? wk : wv);
    float4 g = *reinterpret_cast<const float4*>(src + off);
    f16x4 h = { (_Float16)g.x, (_Float16)g.y, (_Float16)g.z, (_Float16)g.w };
    *reinterpret_cast<f16x4*>(w16 + idx) = h;
}

// ===================== K1: QKV projection (MFMA f16) =====================
// 32 rows/block (grid 512x3 = 1536 blocks). Wave pairs: waves {0,1} rows 0-15,
// waves {2,3} rows 16-31; (w&1) picks col half (2 n-tiles).
__global__ __launch_bounds__(256) void proj(
    const float* __restrict__ query, const float* __restrict__ key,
    const float* __restrict__ value, const _Float16* __restrict__ w16,
    const float* __restrict__ bq, const float* __restrict__ bk, const float* __restrict__ bv,
    _Float16* __restrict__ q16, _Float16* __restrict__ k16, _Float16* __restrict__ vT16)
{
    __shared__ _Float16 xsh[64][36];   // only for the vT transpose epilogue

    const int t = threadIdx.x;
    const int wave = t >> 6, lane = t & 63;
    const int n16 = lane & 15, quad = lane >> 4;
    const int z = blockIdx.y;
    const float* in   = (z == 0) ? query : ((z == 1) ? key : value);
    const float* bias = (z == 0) ? bq    : ((z == 1) ? bk  : bv);
    const _Float16* wz = w16 + z * (DK * DM);
    const int row0 = blockIdx.x * 32;
    const int row_base = row0 + (wave >> 1) * 16;
    const int nt0 = (wave & 1) * 2;                   // this wave's two n-tiles: nt0, nt0+1
    const float* abase = in + (size_t)(row_base + n16) * DM + quad * 8;

    f32x4 acc[2] = {};   // 2 n-tiles of 16 cols each

    float4 p0 = *reinterpret_cast<const float4*>(abase);
    float4 p1 = *reinterpret_cast<const float4*>(abase + 4);
    float4 p2 = *reinterpret_cast<const float4*>(abase + 32);
    float4 p3 = *reinterpret_cast<const float4*>(abase + 36);

    #pragma unroll 2
    for (int kk = 0; kk < DM; kk += 64) {
        f16x8 a0 = { (_Float16)p0.x, (_Float16)p0.y, (_Float16)p0.z, (_Float16)p0.w,
                     (_Float16)p1.x, (_Float16)p1.y, (_Float16)p1.z, (_Float16)p1.w };
        f16x8 a1 = { (_Float16)p2.x, (_Float16)p2.y, (_Float16)p2.z, (_Float16)p2.w,
                     (_Float16)p3.x, (_Float16)p3.y, (_Float16)p3.z, (_Float16)p3.w };
        if (kk < DM - 64) {
            p0 = *reinterpret_cast<const float4*>(abase + kk + 64);
            p1 = *reinterpret_cast<const float4*>(abase + kk + 68);
            p2 = *reinterpret_cast<const float4*>(abase + kk + 96);
            p3 = *reinterpret_cast<const float4*>(abase + kk + 100);
        }
        #pragma unroll
        for (int i = 0; i < 2; ++i) {
            const _Float16* bbase = wz + (size_t)((nt0 + i) * 16 + n16) * DM + kk + quad * 8;
            f16x8 b0 = *reinterpret_cast<const f16x8*>(bbase);
            f16x8 b1 = *reinterpret_cast<const f16x8*>(bbase + 32);
            acc[i] = MFMA16(a0, b0, acc[i]);
            acc[i] = MFMA16(a1, b1, acc[i]);
        }
    }

    const int batch = row0 >> 11, row0s = row0 & (SEQ - 1);
    if (z < 2) {
        _Float16* out = (z == 0) ? q16 : k16;
        #pragma unroll
        for (int i = 0; i < 2; ++i) {
            float bzv = bias[(nt0 + i) * 16 + n16];
            #pragma unroll
            for (int r = 0; r < 4; ++r) {
                int grow = row_base + quad * 4 + r;   // C layout: row=quad*4+reg
                out[(size_t)grow * DK + (nt0 + i) * 16 + n16] = (_Float16)(acc[i][r] + bzv);
            }
        }
    } else {
        #pragma unroll
        for (int i = 0; i < 2; ++i) {
            float bzv = bias[(nt0 + i) * 16 + n16];
            #pragma unroll
            for (int r = 0; r < 4; ++r)
                xsh[(nt0 + i) * 16 + n16][(wave >> 1) * 16 + quad * 4 + r]
                    = (_Float16)(acc[i][r] + bzv);
        }
        __syncthreads();
        int d = t >> 2, s0 = (t & 3) * 8;             // 64 cols x 4 chunks of 8
        _Float16* dst = vT16 + ((size_t)(batch * DK + d)) * SEQ + row0s + s0;
        f16x8 h0;
        #pragma unroll
        for (int j = 0; j < 8; ++j) h0[j] = xsh[d][s0 + j];
        *reinterpret_cast<f16x8*>(dst) = h0;
    }
}

// ===================== K2: fused attention =====================
// Wave-count round: RT=16 (every MFMA row real, round-0 structure) but 16 waves
// (1024 threads)/block. LDS ~79 KB -> 2 blocks/CU, 2x16 = 32 waves/CU (8/SIMD max).
// Per-wave serial work halves in every phase vs round-0; total MFMA count unchanged.
// RT=8 rounds (r2/r3) falsified "more blocks": duplicated MFMA work, no occupancy gain.
#define RT  16
#define SCH 2056   // fp16 row pitch: 4112 B (16B-aligned)

__global__ __launch_bounds__(1024, 4) void attn(
    const _Float16* __restrict__ q16,   // [16384][64]
    const _Float16* __restrict__ k16,   // [16384][64]
    const _Float16* __restrict__ vT16,  // [8][64][2048]
    const int* __restrict__ mask,       // [8][2048][2048]
    float* __restrict__ attno,          // [16384][64]
    float* __restrict__ aw)             // [8][2048][2048]
{
    __shared__ _Float16 sc[RT][SCH];    // scores -> masked s -> exp(s-m), fp16 (~66 KB)
    __shared__ float red[4][3][16][17]; // phase-3 partial-O reduction, 3 partials (~13 KB)
    __shared__ float st_il[RT];

    const int t = threadIdx.x;
    const int wave = t >> 6, lane = t & 63;   // wave 0..15
    const int n16 = lane & 15, quad = lane >> 4;
    const int row0 = blockIdx.x * RT;
    const int batch = row0 >> 11, row0s = row0 & (SEQ - 1);

    // ---------- phase 0: mask -> register bitmask (hides L3/HBM latency under QK) ----------
    // wave w owns row w; this lane covers keys {it*256 + lane*4 .. +3}, it=0..7
    unsigned int mb = 0;
    {
        const int4* mr = reinterpret_cast<const int4*>(
            mask + (size_t)batch * SEQ * SEQ + (size_t)(row0s + wave) * SEQ);
        #pragma unroll
        for (int it = 0; it < 8; ++it) {
            int4 a = mr[it * 64 + lane];
            mb |= ((a.x != 0) ? 1u : 0u) << (it * 4 + 0);
            mb |= ((a.y != 0) ? 1u : 0u) << (it * 4 + 1);
            mb |= ((a.z != 0) ? 1u : 0u) << (it * 4 + 2);
            mb |= ((a.w != 0) ? 1u : 0u) << (it * 4 + 3);
        }
    }

    // ---------- phase 1: scaled scores -> sc (fp16); wave covers cols c*256+wave*16 ----------
    {
        const _Float16* qb = q16 + (size_t)(row0 + n16) * DK + quad * 8;
        f16x8 aq0 = *reinterpret_cast<const f16x8*>(qb);
        f16x8 aq1 = *reinterpret_cast<const f16x8*>(qb + 32);
        const _Float16* kbase = k16 + ((size_t)(batch * SEQ) + wave * 16 + n16) * DK + quad * 8;
        f16x8 b0[2], b1[2];
        b0[0] = *reinterpret_cast<const f16x8*>(kbase);
        b1[0] = *reinterpret_cast<const f16x8*>(kbase + 32);
        b0[1] = *reinterpret_cast<const f16x8*>(kbase + 256 * DK);
        b1[1] = *reinterpret_cast<const f16x8*>(kbase + 256 * DK + 32);
        #pragma unroll
        for (int c = 0; c < 8; ++c) {
            int cur = c & 1;
            f16x8 cb0 = b0[cur], cb1 = b1[cur];
            if (c < 6) {   // depth-2: keep two chunk-loads in flight
                b0[cur] = *reinterpret_cast<const f16x8*>(kbase + (size_t)(c + 2) * 256 * DK);
                b1[cur] = *reinterpret_cast<const f16x8*>(kbase + (size_t)(c + 2) * 256 * DK + 32);
            }
            f32x4 acc = {};
            acc = MFMA16(aq0, cb0, acc);
            acc = MFMA16(aq1, cb1, acc);
            int col = c * 256 + wave * 16 + n16;
            #pragma unroll
            for (int r = 0; r < 4; ++r)
                sc[quad * 4 + r][col] = (_Float16)(acc[r] * 0.125f);
        }
    }
    __syncthreads();

    // ---------- phase 2: pure LDS/VALU softmax, one row per wave ----------
    {
        const int row = wave;

        // pass A: mask/eps fill -> writeback fp16; track max
        float vmax = -3.4e38f;
        #pragma unroll
        for (int it = 0; it < 8; ++it) {
            int j = it * 64 + lane;
            f16x4 s4 = *reinterpret_cast<const f16x4*>(&sc[row][j * 4]);
            float s0 = (float)s4[0], s1 = (float)s4[1], s2 = (float)s4[2], s3 = (float)s4[3];
            s0 = (!((mb >> (it * 4 + 0)) & 1u) || s0 == 0.0f) ? EPSV : s0;
            s1 = (!((mb >> (it * 4 + 1)) & 1u) || s1 == 0.0f) ? EPSV : s1;
            s2 = (!((mb >> (it * 4 + 2)) & 1u) || s2 == 0.0f) ? EPSV : s2;
            s3 = (!((mb >> (it * 4 + 3)) & 1u) || s3 == 0.0f) ? EPSV : s3;
            f16x4 h = { (_Float16)s0, (_Float16)s1, (_Float16)s2, (_Float16)s3 };
            *reinterpret_cast<f16x4*>(&sc[row][j * 4]) = h;
            vmax = fmaxf(vmax, fmaxf(fmaxf(s0, s1), fmaxf(s2, s3)));
        }
        #pragma unroll
        for (int off = 32; off; off >>= 1) vmax = fmaxf(vmax, __shfl_xor(vmax, off));

        // pass B: exp(s - m) -> writeback fp16; track sum
        float vsum = 0.0f;
        #pragma unroll
        for (int it = 0; it < 8; ++it) {
            int j = it * 64 + lane;
            f16x4 s4 = *reinterpret_cast<const f16x4*>(&sc[row][j * 4]);
            float e0 = __expf((float)s4[0] - vmax), e1 = __expf((float)s4[1] - vmax);
            float e2 = __expf((float)s4[2] - vmax), e3 = __expf((float)s4[3] - vmax);
            f16x4 h = { (_Float16)e0, (_Float16)e1, (_Float16)e2, (_Float16)e3 };
            *reinterpret_cast<f16x4*>(&sc[row][j * 4]) = h;
            vsum += (e0 + e1) + (e2 + e3);
        }
        #pragma unroll
        for (int off = 32; off; off >>= 1) vsum += __shfl_xor(vsum, off);
        float il = 1.0f / vsum;
        if (lane == 0) st_il[row] = il;

        // pass C: p = e * il -> aw (nontemporal float4 — write-once data)
        float* awrow = aw + (size_t)batch * SEQ * SEQ + (size_t)(row0s + row) * SEQ;
        #pragma unroll
        for (int it = 0; it < 8; ++it) {
            int j = it * 64 + lane;
            f16x4 e4 = *reinterpret_cast<const f16x4*>(&sc[row][j * 4]);
            f32x4 p4 = { (float)e4[0] * il, (float)e4[1] * il,
                         (float)e4[2] * il, (float)e4[3] * il };
            __builtin_nontemporal_store(p4, reinterpret_cast<f32x4*>(awrow + j * 4));
        }
    }
    __syncthreads();

    // ---------- phase 3: O = (E V) * il — 4-way key-split, depth-2 pipe ----------
    {
        const int dblk = wave & 3, kq = wave >> 2;   // d-block 0..3, key-quarter 0..3
        f32x4 oacc = {};
        const _Float16* vbase = vT16 + ((size_t)(batch * DK + dblk * 16 + n16)) * SEQ
                              + kq * 512 + quad * 8;
        const _Float16* scrow = &sc[n16][kq * 512];
        f16x8 bv0[2], bv1[2];
        bv0[0] = *reinterpret_cast<const f16x8*>(vbase);
        bv1[0] = *reinterpret_cast<const f16x8*>(vbase + 32);
        bv0[1] = *reinterpret_cast<const f16x8*>(vbase + 64);
        bv1[1] = *reinterpret_cast<const f16x8*>(vbase + 96);
        #pragma unroll
        for (int c = 0; c < 8; ++c) {
            int cur = c & 1;
            f16x8 cb0 = bv0[cur], cb1 = bv1[cur];
            if (c < 6) {
                bv0[cur] = *reinterpret_cast<const f16x8*>(vbase + (c + 2) * 64);
                bv1[cur] = *reinterpret_cast<const f16x8*>(vbase + (c + 2) * 64 + 32);
            }
            f16x8 a0 = *reinterpret_cast<const f16x8*>(scrow + c * 64 + quad * 8);
            f16x8 a1 = *reinterpret_cast<const f16x8*>(scrow + c * 64 + 32 + quad * 8);
            oacc = MFMA16(a0, cb0, oacc);
            oacc = MFMA16(a1, cb1, oacc);
        }
        if (kq > 0) {
            #pragma unroll
            for (int r = 0; r < 4; ++r)
                red[dblk][kq - 1][quad * 4 + r][n16] = oacc[r];
        }
        __syncthreads();
        if (kq == 0) {
            #pragma unroll
            for (int r = 0; r < 4; ++r) {
                int row = quad * 4 + r;
                float o = oacc[r] + red[dblk][0][row][n16]
                        + red[dblk][1][row][n16] + red[dblk][2][row][n16];
                attno[(size_t)(row0 + row) * DK + dblk * 16 + n16] = o * st_il[row];
            }
        }
    }
}

// ===================== launch =====================
extern "C" void kernel_launch(void* const* d_in, const int* in_sizes, int n_in,
                              void* d_out, int out_size, void* d_ws, size_t ws_size,
                              hipStream_t stream) {
    const float* query = (const float*)d_in[0];
    const float* key   = (const float*)d_in[1];
    const float* value = (const float*)d_in[2];
    const int*   amask = (const int*)d_in[3];
    const float* Wq = (const float*)d_in[4];
    const float* bq = (const float*)d_in[5];
    const float* Wk = (const float*)d_in[6];
    const float* bk = (const float*)d_in[7];
    const float* Wv = (const float*)d_in[8];
    const float* bv = (const float*)d_in[9];

    float* attno = (float*)d_out;                      // [16384][64]
    float* aw    = attno + (size_t)NROW * DK;          // [8][2048][2048]

    char* ws = (char*)d_ws;
    _Float16* q16  = (_Float16*)(ws);                  // 2 MB
    _Float16* k16  = (_Float16*)(ws + (size_t)2097152);// 2 MB
    _Float16* vT16 = (_Float16*)(ws + (size_t)4194304);// 2 MB
    _Float16* w16  = (_Float16*)(ws + (size_t)6291456);// 192 KB

    wcvt<<<96, 256, 0, stream>>>(Wq, Wk, Wv, w16);
    proj<<<dim3(NROW / 32, 3), 256, 0, stream>>>(query, key, value, w16,
                                                 bq, bk, bv, q16, k16, vT16);
    attn<<<NROW / RT, 1024, 0, stream>>>(q16, k16, vT16, amask, attno, aw);
}